// Round 2
// baseline (136.027 us; speedup 1.0000x reference)
//
#include <hip/hip_runtime.h>
#include <math.h>

#define N_ATOMS   1500
#define NODE_DIM  128
#define HIDDEN    64
#define SPH_DIM   480
#define OFF0      128
#define MUL1E     64
#define HID1E     32
#define NUM_BASIS 20
#define NEDGE     (N_ATOMS * N_ATOMS)          // 2,250,000
#define JTILES    ((N_ATOMS + 255) / 256)      // 6

__device__ __forceinline__ float wave_reduce_sum64(float v) {
#pragma unroll
    for (int m = 1; m <= 32; m <<= 1) v += __shfl_xor(v, m, 64);
    return v;
}
__device__ __forceinline__ float half_reduce_sum32(float v) {
#pragma unroll
    for (int m = 1; m <= 16; m <<= 1) v += __shfl_xor(v, m, 64);
    return v;
}

// Phase 1: one wave per node. Writes float4-packed tables into workspace:
//   a4[n] = (perm(sph_i)*(1+s_i), 0), b4[n] = (perm(sph_j)*(1+s_j), 0),
//   c4[n] = (coord[n], 0)
__global__ __launch_bounds__(64) void node_precompute(
    const float* __restrict__ xs,   const float* __restrict__ xsph,
    const float* __restrict__ coord,
    const float* __restrict__ Wsi1, const float* __restrict__ Wsi2,
    const float* __restrict__ Wsj1, const float* __restrict__ Wsj2,
    const float* __restrict__ Wpi1, const float* __restrict__ Wpi2,
    const float* __restrict__ Wpj1, const float* __restrict__ Wpj2,
    float4* __restrict__ a4, float4* __restrict__ b4, float4* __restrict__ c4) {
    const int n = blockIdx.x;
    const int lane = threadIdx.x;

    // ---- scalar MLPs: silu(x @ W1) @ W2, lane = hidden unit ----
    const float* xr = xs + n * NODE_DIM;
    float zi = 0.f, zj = 0.f;
#pragma unroll 8
    for (int k = 0; k < NODE_DIM; ++k) {
        const float xv = xr[k];                 // broadcast
        zi += xv * Wsi1[k * HIDDEN + lane];     // coalesced
        zj += xv * Wsj1[k * HIDDEN + lane];
    }
    const float pi = zi / (1.f + __expf(-zi)) * Wsi2[lane];
    const float pj = zj / (1.f + __expf(-zj)) * Wsj2[lane];
    const float s_i = wave_reduce_sum64(pi);
    const float s_j = wave_reduce_sum64(pj);

    // ---- spherical 1e MLPs: lanes 0..31 -> Wpi, lanes 32..63 -> Wpj ----
    const int hh = lane & 31;
    const int which = lane >> 5;
    const float* W1 = which ? Wpj1 : Wpi1;      // [64,32]
    const float* W2 = which ? Wpj2 : Wpi2;      // [32,1]
    const float* vr = xsph + n * SPH_DIM + OFF0;
    float a0 = 0.f, a1 = 0.f, a2 = 0.f;
#pragma unroll 4
    for (int m = 0; m < MUL1E; ++m) {
        const float w = W1[m * HID1E + hh];
        a0 += vr[m * 3 + 0] * w;
        a1 += vr[m * 3 + 1] * w;
        a2 += vr[m * 3 + 2] * w;
    }
    a0 *= 0.125f; a1 *= 0.125f; a2 *= 0.125f;   // / sqrt(64)
    const float nrm = sqrtf(a0 * a0 + a1 * a1 + a2 * a2);
    const float gate = 1.f / (1.f + __expf(-nrm));
    const float w2 = W2[hh] * gate * 0.17677669529663687f;  // / sqrt(32)
    const float o0 = half_reduce_sum32(a0 * w2);
    const float o1 = half_reduce_sum32(a1 * w2);
    const float o2 = half_reduce_sum32(a2 * w2);
    // e3nn 1e (y,z,x) -> (x,y,z): result = (o2, o0, o1)
    if (lane == 0) {
        const float s = 1.f + s_i;
        a4[n] = make_float4(o2 * s, o0 * s, o1 * s, 0.f);
    } else if (lane == 32) {
        const float s = 1.f + s_j;
        b4[n] = make_float4(o2 * s, o0 * s, o1 * s, 0.f);
    } else if (lane == 16) {
        c4[n] = make_float4(coord[n * 3], coord[n * 3 + 1], coord[n * 3 + 2], 0.f);
    }
}

// Phase 2: block = (j-tile of 256, i). i is wave-uniform -> scalar loads.
//   out[i*N+j][r][c] = 0.5 * fc(d_ij) * (a_i[r]*b_j[c] + b_i[r]*a_j[c])
// Each block's 256 edges are a contiguous 9216-B output region (16B-aligned).
__global__ __launch_bounds__(256) void edge_kernel(
    const float4* __restrict__ a4, const float4* __restrict__ b4,
    const float4* __restrict__ c4, const float* __restrict__ Wrbf,
    float* __restrict__ out) {
    __shared__ float sm[256 * 9];
    const int i  = blockIdx.y;
    const int j0 = blockIdx.x * 256;
    const int j  = j0 + threadIdx.x;
    const int jj = (j < N_ATOMS) ? j : (N_ATOMS - 1);   // clamp; extras never stored

    const float4 ai = a4[i], bi = b4[i], ci = c4[i];    // uniform
    const float4 aj = a4[jj], bj = b4[jj], cj = c4[jj]; // dwordx4 gathers

    const float dx = ci.x - cj.x, dy = ci.y - cj.y, dz = ci.z - cj.z;
    const float d = sqrtf(dx * dx + dy * dy + dz * dz);

    // fc = 0.5 * sum_k Wrbf[k] * exp(-7.22*(d - 5k/19)^2)
    // direct form: exponent always <= 0, underflows cleanly (no overflow/NaN)
    float fc = 0.f;
#pragma unroll
    for (int k = 0; k < NUM_BASIS; ++k) {
        const float t = d - (float)(5.0 * k / 19.0);
        fc += Wrbf[k] * __expf(-7.22f * (t * t));
    }
    fc *= 0.5f;

    // pre-scale rows by fc: 6 muls, then 9 mul + 9 fma
    const float fa0 = fc * ai.x, fa1 = fc * ai.y, fa2 = fc * ai.z;
    const float fb0 = fc * bi.x, fb1 = fc * bi.y, fb2 = fc * bi.z;

    float c[9];
    c[0] = fa0 * bj.x + fb0 * aj.x;
    c[1] = fa0 * bj.y + fb0 * aj.y;
    c[2] = fa0 * bj.z + fb0 * aj.z;
    c[3] = fa1 * bj.x + fb1 * aj.x;
    c[4] = fa1 * bj.y + fb1 * aj.y;
    c[5] = fa1 * bj.z + fb1 * aj.z;
    c[6] = fa2 * bj.x + fb2 * aj.x;
    c[7] = fa2 * bj.y + fb2 * aj.y;
    c[8] = fa2 * bj.z + fb2 * aj.z;

    // stage edge-major in LDS (stride 9 floats -> 2-way bank alias, free)
#pragma unroll
    for (int t = 0; t < 9; ++t) sm[threadIdx.x * 9 + t] = c[t];
    __syncthreads();

    // coalesced float4 stores of this block's contiguous region
    const int nj  = min(N_ATOMS - j0, 256);
    const int nf4 = nj * 9 / 4;                  // 576 full, 495 tail (exact)
    const float4* sm4 = (const float4*)sm;
    float4* out4 = (float4*)out + ((size_t)i * N_ATOMS + j0) * 9 / 4;
    for (int t = threadIdx.x; t < nf4; t += 256) out4[t] = sm4[t];
}

extern "C" void kernel_launch(void* const* d_in, const int* in_sizes, int n_in,
                              void* d_out, int out_size, void* d_ws, size_t ws_size,
                              hipStream_t stream) {
    const float* x_scalar = (const float*)d_in[0];
    const float* x_sph    = (const float*)d_in[1];
    const float* coord    = (const float*)d_in[2];
    // d_in[3] = fc_edge_index (int32) — known i-major full graph, unused
    const float* Wsi1 = (const float*)d_in[4];
    const float* Wsi2 = (const float*)d_in[5];
    const float* Wsj1 = (const float*)d_in[6];
    const float* Wsj2 = (const float*)d_in[7];
    const float* Wpi1 = (const float*)d_in[8];
    const float* Wpi2 = (const float*)d_in[9];
    const float* Wpj1 = (const float*)d_in[10];
    const float* Wpj2 = (const float*)d_in[11];
    const float* Wrbf = (const float*)d_in[12];
    float* out = (float*)d_out;

    float4* a4 = (float4*)d_ws;          // [N]
    float4* b4 = a4 + N_ATOMS;           // [N]
    float4* c4 = b4 + N_ATOMS;           // [N]

    node_precompute<<<N_ATOMS, 64, 0, stream>>>(
        x_scalar, x_sph, coord, Wsi1, Wsi2, Wsj1, Wsj2,
        Wpi1, Wpi2, Wpj1, Wpj2, a4, b4, c4);

    dim3 grid(JTILES, N_ATOMS);          // (6, 1500)
    edge_kernel<<<grid, 256, 0, stream>>>(a4, b4, c4, Wrbf, out);
}

// Round 5
// 135.455 us; speedup vs baseline: 1.0042x; 1.0042x over previous
//
#include <hip/hip_runtime.h>
#include <math.h>

#define N_ATOMS   1500
#define NODE_DIM  128
#define HIDDEN    64
#define SPH_DIM   480
#define OFF0      128
#define MUL1E     64
#define HID1E     32
#define NUM_BASIS 20
#define NEDGE     (N_ATOMS * N_ATOMS)          // 2,250,000
#define JTILES    ((N_ATOMS + 255) / 256)      // 6

__device__ __forceinline__ float wave_reduce_sum64(float v) {
#pragma unroll
    for (int m = 1; m <= 32; m <<= 1) v += __shfl_xor(v, m, 64);
    return v;
}
__device__ __forceinline__ float half_reduce_sum32(float v) {
#pragma unroll
    for (int m = 1; m <= 16; m <<= 1) v += __shfl_xor(v, m, 64);
    return v;
}

// Phase 1: 375 blocks x 256 threads; wave w of block b handles node n = 4b+w.
// Writes float4-packed tables into workspace:
//   a4[n] = (perm(sph_i)*(1+s_i), 0), b4[n] = (perm(sph_j)*(1+s_j), 0),
//   c4[n] = (coord[n], 0)
__global__ __launch_bounds__(256) void node_precompute(
    const float* __restrict__ xs,   const float* __restrict__ xsph,
    const float* __restrict__ coord,
    const float* __restrict__ Wsi1, const float* __restrict__ Wsi2,
    const float* __restrict__ Wsj1, const float* __restrict__ Wsj2,
    const float* __restrict__ Wpi1, const float* __restrict__ Wpi2,
    const float* __restrict__ Wpj1, const float* __restrict__ Wpj2,
    float4* __restrict__ a4, float4* __restrict__ b4, float4* __restrict__ c4) {
    const int n = blockIdx.x * 4 + (threadIdx.x >> 6);   // 375*4 = 1500 exact
    const int lane = threadIdx.x & 63;

    // ---- scalar MLPs: silu(x @ W1) @ W2, lane = hidden unit ----
    const float* xr = xs + n * NODE_DIM;
    float zi = 0.f, zj = 0.f;
#pragma unroll 8
    for (int k = 0; k < NODE_DIM; ++k) {
        const float xv = xr[k];                 // broadcast
        zi += xv * Wsi1[k * HIDDEN + lane];     // coalesced
        zj += xv * Wsj1[k * HIDDEN + lane];
    }
    const float pi = zi / (1.f + __expf(-zi)) * Wsi2[lane];
    const float pj = zj / (1.f + __expf(-zj)) * Wsj2[lane];
    const float s_i = wave_reduce_sum64(pi);
    const float s_j = wave_reduce_sum64(pj);

    // ---- spherical 1e MLPs: lanes 0..31 -> Wpi, lanes 32..63 -> Wpj ----
    const int hh = lane & 31;
    const int which = lane >> 5;
    const float* W1 = which ? Wpj1 : Wpi1;      // [64,32]
    const float* W2 = which ? Wpj2 : Wpi2;      // [32,1]
    const float* vr = xsph + n * SPH_DIM + OFF0;
    float a0 = 0.f, a1 = 0.f, a2 = 0.f;
#pragma unroll 4
    for (int m = 0; m < MUL1E; ++m) {
        const float w = W1[m * HID1E + hh];
        a0 += vr[m * 3 + 0] * w;
        a1 += vr[m * 3 + 1] * w;
        a2 += vr[m * 3 + 2] * w;
    }
    a0 *= 0.125f; a1 *= 0.125f; a2 *= 0.125f;   // / sqrt(64)
    const float nrm = sqrtf(a0 * a0 + a1 * a1 + a2 * a2);
    const float gate = 1.f / (1.f + __expf(-nrm));
    const float w2 = W2[hh] * gate * 0.17677669529663687f;  // / sqrt(32)
    const float o0 = half_reduce_sum32(a0 * w2);
    const float o1 = half_reduce_sum32(a1 * w2);
    const float o2 = half_reduce_sum32(a2 * w2);
    // e3nn 1e (y,z,x) -> (x,y,z): result = (o2, o0, o1)
    if (lane == 0) {
        const float s = 1.f + s_i;
        a4[n] = make_float4(o2 * s, o0 * s, o1 * s, 0.f);
    } else if (lane == 32) {
        const float s = 1.f + s_j;
        b4[n] = make_float4(o2 * s, o0 * s, o1 * s, 0.f);
    } else if (lane == 16) {
        c4[n] = make_float4(coord[n * 3], coord[n * 3 + 1], coord[n * 3 + 2], 0.f);
    }
}

// Phase 2: block = (j-tile of 256, i). i is wave-uniform -> scalar loads.
//   out[i*N+j][r][c] = 0.5 * fc(d_ij) * (a_i[r]*b_j[c] + b_i[r]*a_j[c])
// Contiguous per-block output region, plain temporal float4 stores.
// NOTE: nontemporal stores are disqualified here — the harness's 0xAA poison
// fill leaves dirty d_out lines in L2, and their later eviction overwrites
// NT-stored data (verified divergence in round 4). Plain stores only.
__global__ __launch_bounds__(256) void edge_kernel(
    const float4* __restrict__ a4, const float4* __restrict__ b4,
    const float4* __restrict__ c4, const float* __restrict__ Wrbf,
    float* __restrict__ out) {
    __shared__ float sm[256 * 9];
    const int i  = blockIdx.y;
    const int j0 = blockIdx.x * 256;
    const int j  = j0 + threadIdx.x;
    const int jj = (j < N_ATOMS) ? j : (N_ATOMS - 1);   // clamp; extras never stored

    const float4 ai = a4[i], bi = b4[i], ci = c4[i];    // uniform
    const float4 aj = a4[jj], bj = b4[jj], cj = c4[jj]; // dwordx4 gathers

    const float dx = ci.x - cj.x, dy = ci.y - cj.y, dz = ci.z - cj.z;
    const float d = sqrtf(dx * dx + dy * dy + dz * dz);

    // fc = 0.5 * sum_k Wrbf[k] * exp(-7.22*(d - 5k/19)^2)
    // direct form: exponent always <= 0, underflows cleanly (no overflow/NaN)
    float fc = 0.f;
#pragma unroll
    for (int k = 0; k < NUM_BASIS; ++k) {
        const float t = d - (float)(5.0 * k / 19.0);
        fc += Wrbf[k] * __expf(-7.22f * (t * t));
    }
    fc *= 0.5f;

    // pre-scale rows by fc: 6 muls, then 9 mul + 9 fma
    const float fa0 = fc * ai.x, fa1 = fc * ai.y, fa2 = fc * ai.z;
    const float fb0 = fc * bi.x, fb1 = fc * bi.y, fb2 = fc * bi.z;

    float c[9];
    c[0] = fa0 * bj.x + fb0 * aj.x;
    c[1] = fa0 * bj.y + fb0 * aj.y;
    c[2] = fa0 * bj.z + fb0 * aj.z;
    c[3] = fa1 * bj.x + fb1 * aj.x;
    c[4] = fa1 * bj.y + fb1 * aj.y;
    c[5] = fa1 * bj.z + fb1 * aj.z;
    c[6] = fa2 * bj.x + fb2 * aj.x;
    c[7] = fa2 * bj.y + fb2 * aj.y;
    c[8] = fa2 * bj.z + fb2 * aj.z;

    // stage edge-major in LDS (stride 9 floats -> 2-way bank alias, free)
#pragma unroll
    for (int t = 0; t < 9; ++t) sm[threadIdx.x * 9 + t] = c[t];
    __syncthreads();

    // coalesced float4 stores of this block's contiguous region
    const int nj  = min(N_ATOMS - j0, 256);
    const int nf4 = nj * 9 / 4;                  // 576 full, 495 tail (exact)
    const float4* sm4 = (const float4*)sm;
    float4* out4 = (float4*)out + ((size_t)i * N_ATOMS + j0) * 9 / 4;
    for (int t = threadIdx.x; t < nf4; t += 256) out4[t] = sm4[t];
}

extern "C" void kernel_launch(void* const* d_in, const int* in_sizes, int n_in,
                              void* d_out, int out_size, void* d_ws, size_t ws_size,
                              hipStream_t stream) {
    const float* x_scalar = (const float*)d_in[0];
    const float* x_sph    = (const float*)d_in[1];
    const float* coord    = (const float*)d_in[2];
    // d_in[3] = fc_edge_index (int32) — known i-major full graph, unused
    const float* Wsi1 = (const float*)d_in[4];
    const float* Wsi2 = (const float*)d_in[5];
    const float* Wsj1 = (const float*)d_in[6];
    const float* Wsj2 = (const float*)d_in[7];
    const float* Wpi1 = (const float*)d_in[8];
    const float* Wpi2 = (const float*)d_in[9];
    const float* Wpj1 = (const float*)d_in[10];
    const float* Wpj2 = (const float*)d_in[11];
    const float* Wrbf = (const float*)d_in[12];
    float* out = (float*)d_out;

    float4* a4 = (float4*)d_ws;          // [N]
    float4* b4 = a4 + N_ATOMS;           // [N]
    float4* c4 = b4 + N_ATOMS;           // [N]

    node_precompute<<<375, 256, 0, stream>>>(
        x_scalar, x_sph, coord, Wsi1, Wsi2, Wsj1, Wsj2,
        Wpi1, Wpi2, Wpj1, Wpj2, a4, b4, c4);

    dim3 grid(JTILES, N_ATOMS);          // (6, 1500)
    edge_kernel<<<grid, 256, 0, stream>>>(a4, b4, c4, Wrbf, out);
}